// Round 1
// baseline (307.223 us; speedup 1.0000x reference)
//
#include <hip/hip_runtime.h>

// Problem constants (from reference): B=2, L=2048, D=1024, N=16
#define PS_B  2
#define PS_L  2048
#define PS_DN 16384            // D*N
#define PS_CH (PS_B * PS_DN)   // 32768 independent channels

// One thread per (b, d, n) channel; sequential scan over t.
// Memory layout A[B][L][D][N]: for fixed t, channels are contiguous ->
// each wave's 64 lanes load 256 contiguous bytes per array per step.
__global__ __launch_bounds__(64) void pscan_seq_kernel(
    const float* __restrict__ A,
    const float* __restrict__ X,
    float* __restrict__ H)
{
    const int tid = blockIdx.x * blockDim.x + threadIdx.x;   // 0 .. 32767
    const int b   = tid >> 14;                                // / PS_DN
    const int ch  = tid & (PS_DN - 1);                        // % PS_DN

    const long base = (long)b * PS_L * PS_DN + ch;
    const float* __restrict__ a = A + base;
    const float* __restrict__ x = X + base;
    float*       __restrict__ h = H + base;

    float carry = 0.0f;
    #pragma unroll 8
    for (int t = 0; t < PS_L; ++t) {
        const long off = (long)t * PS_DN;
        const float at = a[off];
        const float xt = x[off];
        carry = fmaf(at, carry, xt);
        h[off] = carry;
    }
}

extern "C" void kernel_launch(void* const* d_in, const int* in_sizes, int n_in,
                              void* d_out, int out_size, void* d_ws, size_t ws_size,
                              hipStream_t stream)
{
    const float* A = (const float*)d_in[0];
    const float* X = (const float*)d_in[1];
    float* H = (float*)d_out;

    const int threads = 64;
    const int blocks  = PS_CH / threads;   // 512 blocks -> 2 waves/CU
    pscan_seq_kernel<<<blocks, threads, 0, stream>>>(A, X, H);
}

// Round 2
// 154.903 us; speedup vs baseline: 1.9833x; 1.9833x over previous
//
#include <hip/hip_runtime.h>

// Problem constants: B=2, L=2048, D=1024, N=16
#define PS_B  2
#define PS_L  2048
#define PS_DN 16384            // D*N
#define PS_CH (PS_B * PS_DN)   // 32768 independent channels
#define U     16               // timesteps per register block
#define NB    (PS_L / U)       // 128 blocks (even)

// One thread per channel, sequential over t, with explicit double-buffered
// register staging: load block k+1 (32 loads, 8KB/wave in flight) while
// computing+storing block k. Named aA/aB buffers keep all indexing
// compile-time constant (no scratch).
__global__ __launch_bounds__(64) void pscan_pipe_kernel(
    const float* __restrict__ A,
    const float* __restrict__ X,
    float* __restrict__ H)
{
    const int tid = blockIdx.x * 64 + threadIdx.x;   // 0 .. 32767
    const int b   = tid >> 14;
    const int ch  = tid & (PS_DN - 1);

    const size_t base = (size_t)b * PS_L * PS_DN + ch;
    const float* __restrict__ a = A + base;
    const float* __restrict__ x = X + base;
    float*       __restrict__ h = H + base;

    float aA[U], xA[U], aB[U], xB[U];

    // Prologue: stage block 0 into A-buffers.
    #pragma unroll
    for (int i = 0; i < U; ++i) {
        const size_t off = (size_t)i * PS_DN;
        aA[i] = a[off];
        xA[i] = x[off];
    }

    float carry = 0.0f;
    for (int k = 0; k < NB; k += 2) {
        // Stage block k+1 into B (independent of A-compute; issues first).
        {
            const size_t boff = (size_t)(k + 1) * U * PS_DN;
            #pragma unroll
            for (int i = 0; i < U; ++i) {
                const size_t off = boff + (size_t)i * PS_DN;
                aB[i] = a[off];
                xB[i] = x[off];
            }
        }
        // Compute + store block k from A-buffers.
        {
            const size_t boff = (size_t)k * U * PS_DN;
            #pragma unroll
            for (int i = 0; i < U; ++i) {
                carry = fmaf(aA[i], carry, xA[i]);
                h[boff + (size_t)i * PS_DN] = carry;
            }
        }
        // Stage block k+2 into A (skip on last iteration).
        if (k + 2 < NB) {
            const size_t boff = (size_t)(k + 2) * U * PS_DN;
            #pragma unroll
            for (int i = 0; i < U; ++i) {
                const size_t off = boff + (size_t)i * PS_DN;
                aA[i] = a[off];
                xA[i] = x[off];
            }
        }
        // Compute + store block k+1 from B-buffers.
        {
            const size_t boff = (size_t)(k + 1) * U * PS_DN;
            #pragma unroll
            for (int i = 0; i < U; ++i) {
                carry = fmaf(aB[i], carry, xB[i]);
                h[boff + (size_t)i * PS_DN] = carry;
            }
        }
    }
}

extern "C" void kernel_launch(void* const* d_in, const int* in_sizes, int n_in,
                              void* d_out, int out_size, void* d_ws, size_t ws_size,
                              hipStream_t stream)
{
    const float* A = (const float*)d_in[0];
    const float* X = (const float*)d_in[1];
    float* H = (float*)d_out;

    const int threads = 64;
    const int blocks  = PS_CH / threads;   // 512 blocks
    pscan_pipe_kernel<<<blocks, threads, 0, stream>>>(A, X, H);
}